// Round 9
// baseline (349.147 us; speedup 1.0000x reference)
//
#include <hip/hip_runtime.h>
#include <hip/hip_bf16.h>

#define TB 512

typedef __attribute__((ext_vector_type(8))) short bf16x8;
typedef __attribute__((ext_vector_type(4))) float f32x4;
typedef __attribute__((ext_vector_type(4))) int   i32x4;

static __device__ __forceinline__ int pk2(float a, float b) {
    __hip_bfloat162 h = __float22bfloat162_rn(float2{a, b});
    int r;
    __builtin_memcpy(&r, &h, 4);
    return r;
}

static __device__ __forceinline__ bf16x8 cvt8(f32x4 lo, f32x4 hi) {
    union { bf16x8 v; __hip_bfloat162 h[4]; } u;
    u.h[0] = __float22bfloat162_rn(float2{lo[0], lo[1]});
    u.h[1] = __float22bfloat162_rn(float2{lo[2], lo[3]});
    u.h[2] = __float22bfloat162_rn(float2{hi[0], hi[1]});
    u.h[3] = __float22bfloat162_rn(float2{hi[2], hi[3]});
    return u.v;
}

// Stage-once / barrier-free-K structure.
// Block = 64 m-rows x full N=512 of one batch. The whole K=512 extent of the
// X slab is staged to LDS as bf16 ONCE (64x512x2B = 64KB exactly), via full
// 2KB contiguous row reads (X fetched exactly once chip-wide, DRAM-friendly),
// then 16 K-steps run with NO barriers: A from LDS, W register-direct from L2
// (W[b]=1MB resident per-XCD; all concurrent blocks share a batch since
// batch = blk>>7 and dispatch round-robins slabs first).
// LDS bank plan (rule 21, both-sides XOR): byte ^= (row&7)<<4. Write: lane=row,
// bits[4:6]=j -> j^(row&7): 8-lane phases hit 8 distinct bank-quads. Read:
// 16 lanes share fk, rows 0..15 -> quad = const^(row&7): 2-way (free, m136).
__global__ __launch_bounds__(TB) void bgemm_bt_bias(
    const float* __restrict__ X,     // [8, 8192, 512]
    const float* __restrict__ Wt,    // [8, 512, 512]
    const float* __restrict__ Bias,  // [8, 512]
    float* __restrict__ Out)         // [8, 8192, 512]
{
    const int blk  = blockIdx.x;          // 0..1023
    const int b    = blk >> 7;            // batch
    const int slab = blk & 127;           // 64-row m-slab
    const int m0   = slab * 64;

    const int tid  = threadIdx.x;
    const int lane = tid & 63;
    const int wave = tid >> 6;            // 0..7: staging k-chunk AND n-group
    const int n0w  = wave * 64;

    const int frow = lane & 15;           // fragment row (m for A, n for B)
    const int fk   = (lane >> 4) * 8;     // fragment k-offset {0,8,16,24}

    __shared__ short Xs[64 * 512];        // 64 KB, bf16, XOR-swizzled

    // W frag pointers (R7-verified addressing); frag nf adds nf*16 rows
    const float* wbase = Wt + ((size_t)b * 512 + n0w + frow) * 512 + fk;

    f32x4 w0[4][2], w1[4][2];             // depth-1 pipelined W sets (named: stays in regs)

#define LW(DST, t) do {                                                         \
    _Pragma("unroll")                                                           \
    for (int nf = 0; nf < 4; ++nf) {                                            \
        DST[nf][0] = *(const f32x4*)(wbase + (size_t)nf * 16 * 512 + (t) * 32); \
        DST[nf][1] = *(const f32x4*)(wbase + (size_t)nf * 16 * 512 + (t) * 32 + 4); \
    }                                                                           \
} while (0)

    // issue first W set early; lands under the staging phase
    LW(w0, 0);

    // ---- one-time X stage: lane owns row `lane`, wave owns 64-float chunk ----
    {
        const float* xrow = X + ((size_t)b * 8192 + m0 + lane) * 512 + wave * 64;
        const int rsw = (lane & 7) << 4;                  // row XOR for swizzle
#pragma unroll
        for (int j = 0; j < 8; ++j) {
            f32x4 lo = *(const f32x4*)(xrow + j * 8);
            f32x4 hi = *(const f32x4*)(xrow + j * 8 + 4);
            i32x4 pw;
            pw[0] = pk2(lo[0], lo[1]); pw[1] = pk2(lo[2], lo[3]);
            pw[2] = pk2(hi[0], hi[1]); pw[3] = pk2(hi[2], hi[3]);
            const int byteoff = (lane * 1024 + wave * 128 + j * 16) ^ rsw;
            *(i32x4*)((char*)Xs + byteoff) = pw;
        }
    }
    __syncthreads();

    f32x4 acc[4][4];
#pragma unroll
    for (int i = 0; i < 4; ++i)
#pragma unroll
        for (int j = 0; j < 4; ++j)
            acc[i][j] = (f32x4){0.f, 0.f, 0.f, 0.f};

#define STEP(t, WS) do {                                                        \
    bf16x8 af[4], bfr[4];                                                       \
    _Pragma("unroll")                                                           \
    for (int mf = 0; mf < 4; ++mf) {                                            \
        const int r = mf * 16 + frow;                                           \
        const int byteoff = (r * 1024 + (t) * 64 + fk * 2) ^ ((r & 7) << 4);    \
        af[mf] = *(const bf16x8*)((const char*)Xs + byteoff);                   \
    }                                                                           \
    _Pragma("unroll")                                                           \
    for (int nf = 0; nf < 4; ++nf)                                              \
        bfr[nf] = cvt8(WS[nf][0], WS[nf][1]);                                   \
    _Pragma("unroll")                                                           \
    for (int mf = 0; mf < 4; ++mf)                                              \
        _Pragma("unroll")                                                       \
        for (int nf = 0; nf < 4; ++nf)                                          \
            acc[mf][nf] = __builtin_amdgcn_mfma_f32_16x16x32_bf16(              \
                af[mf], bfr[nf], acc[mf][nf], 0, 0, 0);                         \
} while (0)

    // barrier-free K-loop, depth-1 W pipeline (issue t+1 before consuming t)
#pragma unroll
    for (int ks = 0; ks < 16; ks += 2) {
        LW(w1, ks + 1);
        STEP(ks, w0);
        if (ks + 2 < 16) LW(w0, ks + 2);
        STEP(ks + 1, w1);
    }
#undef STEP
#undef LW

    // ---- epilogue: add bias, store fp32 ----
    float bv[4];
    const float* biasp = Bias + (size_t)b * 512 + n0w;
#pragma unroll
    for (int nf = 0; nf < 4; ++nf)
        bv[nf] = biasp[nf * 16 + frow];

    float* outp = Out + ((size_t)b * 8192 + m0) * 512 + n0w;
    const int orow = (lane >> 4) * 4;   // C/D: row = (lane>>4)*4 + reg
#pragma unroll
    for (int mf = 0; mf < 4; ++mf)
#pragma unroll
        for (int nf = 0; nf < 4; ++nf)
#pragma unroll
            for (int r = 0; r < 4; ++r)
                outp[(size_t)(mf * 16 + orow + r) * 512 + nf * 16 + frow] =
                    acc[mf][nf][r] + bv[nf];
}

extern "C" void kernel_launch(void* const* d_in, const int* in_sizes, int n_in,
                              void* d_out, int out_size, void* d_ws, size_t ws_size,
                              hipStream_t stream) {
    const float* X    = (const float*)d_in[0];
    const float* Wt   = (const float*)d_in[1];
    const float* Bias = (const float*)d_in[2];
    float* Out        = (float*)d_out;

    dim3 grid(1024);
    bgemm_bt_bias<<<grid, TB, 0, stream>>>(X, Wt, Bias, Out);
}

// Round 10
// 299.693 us; speedup vs baseline: 1.1650x; 1.1650x over previous
//
#include <hip/hip_runtime.h>
#include <hip/hip_bf16.h>

#define TB 512

typedef __attribute__((ext_vector_type(8))) short bf16x8;
typedef __attribute__((ext_vector_type(4))) float f32x4;

// async global->LDS, 16B/lane: per-lane GLOBAL address, wave-uniform LDS base
// (HW adds lane*16). Fire-and-forget: no dest VGPR, so the compiler CANNOT
// collapse the pipeline by sinking loads to their uses (R7/R9 failure mode).
static __device__ __forceinline__ void gload_lds16(const float* g, float* l) {
    __builtin_amdgcn_global_load_lds(
        (const __attribute__((address_space(1))) void*)g,
        (__attribute__((address_space(3))) void*)l, 16, 0, 0);
}

// 8 consecutive fp32 -> bf16x8 (RNE)
static __device__ __forceinline__ bf16x8 cvt8(f32x4 lo, f32x4 hi) {
    union { bf16x8 v; __hip_bfloat162 h[4]; } u;
    u.h[0] = __float22bfloat162_rn(float2{lo[0], lo[1]});
    u.h[1] = __float22bfloat162_rn(float2{lo[2], lo[3]});
    u.h[2] = __float22bfloat162_rn(float2{hi[0], hi[1]});
    u.h[3] = __float22bfloat162_rn(float2{hi[2], hi[3]});
    return u.v;
}

// T3/T4 counted-vmcnt pipeline (m218 pattern, m201 precedent for 1 blk/CU):
// 4 LDS buffers, prefetch distance 3, raw s_barrier, vmcnt(8) leaves 2 tiles
// in flight ACROSS the barrier (~2400cy cover vs ~900cy HBM latency).
// WAR safety: STAGE target buf (ks+3)%4 was last READ at iter ks-1; every
// wave's ds_reads of that iter completed before its end-of-iter barrier
// (MFMA operand waits + explicit lgkmcnt(0)), so overwrite after the barrier
// is race-free with a single barrier per K-step.
// LDS bank plan (rule 21, R8/R9-verified): 16B-slot ^= (row&7); write side via
// pre-swizzled GLOBAL source slot (l&7)^(l>>3) with linear gload dest; read
// side same XOR -> A/B frag reads are 2-way (free, m136).
__global__ __launch_bounds__(TB) void bgemm_bt_bias(
    const float* __restrict__ X,     // [8, 8192, 512]
    const float* __restrict__ Wt,    // [8, 512, 512]
    const float* __restrict__ Bias,  // [8, 512]
    float* __restrict__ Out)         // [8, 8192, 512]
{
    // XCD-aware swizzle: 4 n-tiles sharing an x-panel land on one XCD
    const int flat  = blockIdx.x;          // 0..2047
    const int xcd   = flat & 7;
    const int rr    = flat >> 3;
    const int nt    = rr & 3;
    const int p     = rr >> 2;
    const int panel = p * 8 + xcd;         // 0..511 = batch*64 + mtile
    const int mt    = panel & 63;
    const int b     = panel >> 6;

    const int m0  = mt * 128;
    const int n0  = nt * 128;
    const int tid = threadIdx.x;
    const int lane = tid & 63;
    const int wave = tid >> 6;             // 0..7
    const int wm = (wave >> 2) * 64;       // 2 m-groups
    const int wn = (wave & 3) * 32;        // 4 n-groups

    const int frow = lane & 15;            // fragment row
    const int fk   = (lane >> 4) * 8;      // fragment k-offset {0,8,16,24}

    __shared__ float As[4][128 * 32];      // 4 x 16KB fp32
    __shared__ float Bs[4][128 * 32];      // 4 x 16KB fp32  (total 128KB)

    // staging: thread t feeds row t>>3 (0..63) and row+64; global col-slot
    // pre-swizzled so linear LDS dest yields slot^=(row&7) layout
    const int srow  = tid >> 3;
    const int sslot = (tid & 7) ^ (srow & 7);
    const float* xlane = X  + ((size_t)b * 8192 + m0 + srow) * 512 + sslot * 4;
    const float* wlane = Wt + ((size_t)b * 512  + n0 + srow) * 512 + sslot * 4;

#define STAGE(buf, t) do {                                                      \
    gload_lds16(xlane + (t) * 32,                 &As[buf][(wave * 8) * 32]);   \
    gload_lds16(xlane + 64 * 512 + (t) * 32,      &As[buf][(64 + wave * 8) * 32]); \
    gload_lds16(wlane + (t) * 32,                 &Bs[buf][(wave * 8) * 32]);   \
    gload_lds16(wlane + 64 * 512 + (t) * 32,      &Bs[buf][(64 + wave * 8) * 32]); \
} while (0)

#define COMPUTE(cur) do {                                                       \
    bf16x8 af[4], bfr[2];                                                       \
    const char* Ab = (const char*)&As[cur][0];                                  \
    const char* Bb = (const char*)&Bs[cur][0];                                  \
    _Pragma("unroll")                                                           \
    for (int mf = 0; mf < 4; ++mf) {                                            \
        const int r = wm + mf * 16 + frow;                                      \
        const int sw = (r & 7) << 4;                                            \
        f32x4 lo = *(const f32x4*)(Ab + ((r * 128 + fk * 4) ^ sw));             \
        f32x4 hi = *(const f32x4*)(Ab + ((r * 128 + fk * 4 + 16) ^ sw));        \
        af[mf] = cvt8(lo, hi);                                                  \
    }                                                                           \
    _Pragma("unroll")                                                           \
    for (int nf = 0; nf < 2; ++nf) {                                            \
        const int r = wn + nf * 16 + frow;                                      \
        const int sw = (r & 7) << 4;                                            \
        f32x4 lo = *(const f32x4*)(Bb + ((r * 128 + fk * 4) ^ sw));             \
        f32x4 hi = *(const f32x4*)(Bb + ((r * 128 + fk * 4 + 16) ^ sw));        \
        bfr[nf] = cvt8(lo, hi);                                                 \
    }                                                                           \
    _Pragma("unroll")                                                           \
    for (int mf = 0; mf < 4; ++mf)                                              \
        _Pragma("unroll")                                                       \
        for (int nf = 0; nf < 2; ++nf)                                          \
            acc[mf][nf] = __builtin_amdgcn_mfma_f32_16x16x32_bf16(              \
                af[mf], bfr[nf], acc[mf][nf], 0, 0, 0);                         \
} while (0)

    f32x4 acc[4][2];
#pragma unroll
    for (int i = 0; i < 4; ++i)
#pragma unroll
        for (int j = 0; j < 2; ++j)
            acc[i][j] = (f32x4){0.f, 0.f, 0.f, 0.f};

    // ---- prologue: fill 3 of 4 buffers, wait only for tile 0 (vmcnt 8) ----
    STAGE(0, 0);
    STAGE(1, 1);
    STAGE(2, 2);
    __builtin_amdgcn_sched_barrier(0);
    asm volatile("s_waitcnt vmcnt(8)" ::: "memory");
    __builtin_amdgcn_s_barrier();
    __builtin_amdgcn_sched_barrier(0);

    // ---- main loop: counted vmcnt, never drained to 0 until the tail ----
#pragma unroll
    for (int ks = 0; ks < 16; ++ks) {
        COMPUTE(ks & 3);
        if (ks + 3 < 16) STAGE((ks + 3) & 3, ks + 3);
        if (ks < 15) {
            __builtin_amdgcn_sched_barrier(0);
            asm volatile("s_waitcnt lgkmcnt(0)" ::: "memory");   // ds_reads surely done (cheap insurance)
            if (ks < 13)       asm volatile("s_waitcnt vmcnt(8)" ::: "memory"); // ks+1 ready; ks+2,ks+3 in flight
            else if (ks == 13) asm volatile("s_waitcnt vmcnt(4)" ::: "memory"); // t14 ready; t15 in flight
            else               asm volatile("s_waitcnt vmcnt(0)" ::: "memory"); // t15 ready
            __builtin_amdgcn_s_barrier();
            __builtin_amdgcn_sched_barrier(0);
        }
    }
#undef COMPUTE
#undef STAGE

    // ---- epilogue: add bias, store fp32 ----
    float bv[2];
    const float* biasp = Bias + (size_t)b * 512 + n0 + wn;
#pragma unroll
    for (int nf = 0; nf < 2; ++nf)
        bv[nf] = biasp[nf * 16 + frow];

    float* outp = Out + ((size_t)b * 8192 + m0 + wm) * 512 + n0 + wn;
    const int orow = (lane >> 4) * 4;   // C/D: row = (lane>>4)*4 + reg
#pragma unroll
    for (int mf = 0; mf < 4; ++mf)
#pragma unroll
        for (int nf = 0; nf < 2; ++nf)
#pragma unroll
            for (int r = 0; r < 4; ++r)
                outp[(size_t)(mf * 16 + orow + r) * 512 + nf * 16 + frow] =
                    acc[mf][nf][r] + bv[nf];
}

extern "C" void kernel_launch(void* const* d_in, const int* in_sizes, int n_in,
                              void* d_out, int out_size, void* d_ws, size_t ws_size,
                              hipStream_t stream) {
    const float* X    = (const float*)d_in[0];
    const float* Wt   = (const float*)d_in[1];
    const float* Bias = (const float*)d_in[2];
    float* Out        = (float*)d_out;

    dim3 grid(2048);
    bgemm_bt_bias<<<grid, TB, 0, stream>>>(X, Wt, Bias, Out);
}

// Round 14
// 278.840 us; speedup vs baseline: 1.2521x; 1.0748x over previous
//
#include <hip/hip_runtime.h>
#include <hip/hip_bf16.h>

#define BM 128
#define BN 128
#define BK 32
#define TB 512
#define LDK 40   // padded LDS row stride (80 B): b128 frag reads conflict-free,
                 // 16B slab writes <=2-way (free per m136)

typedef __attribute__((ext_vector_type(8))) short bf16x8;
typedef __attribute__((ext_vector_type(4))) float f32x4;
typedef __attribute__((ext_vector_type(4))) int   i32x4;

static __device__ inline int pk2(float a, float b) {
    // two fp32 -> packed bf16 (RNE)
    __hip_bfloat162 h = __float22bfloat162_rn(float2{a, b});
    int r;
    __builtin_memcpy(&r, &h, 4);
    return r;
}

// Baseline structure (best measured: 120.8us) with ONE change: 512-thread
// blocks on the same 128x128 tile. 8 waves of 64x32 each. Rationale: all
// pipes <25% busy and the only filler of a barrier-synced block's stall is
// another resident wave-group; 4-wave blocks gave ~9 waves/CU, 8-wave blocks
// at the same 40KB LDS give ~24 waves/CU (3 blocks x 8 waves, 6/SIMD).
__global__ __launch_bounds__(TB) void bgemm_bt_bias(
    const float* __restrict__ X,     // [8, 8192, 512]
    const float* __restrict__ Wt,    // [8, 512, 512]
    const float* __restrict__ Bias,  // [8, 512]
    float* __restrict__ Out)         // [8, 8192, 512]
{
    // XCD-aware swizzle: 4 n-tiles sharing an x-panel land on one XCD
    const int flat  = blockIdx.x;          // 0..2047
    const int xcd   = flat & 7;
    const int rr    = flat >> 3;
    const int nt    = rr & 3;
    const int p     = rr >> 2;
    const int panel = p * 8 + xcd;
    const int mt    = panel & 63;
    const int b     = panel >> 6;

    const int m0  = mt * BM;
    const int n0  = nt * BN;
    const int tid = threadIdx.x;
    const int lane = tid & 63;
    const int wave = tid >> 6;             // 0..7
    const int wm = (wave >> 2) * 64;       // 2 m-groups {0,64}
    const int wn = (wave & 3) * 32;        // 4 n-groups {0,32,64,96}

    __shared__ short As[2][BM * LDK];
    __shared__ short Bs[2][BN * LDK];

    // ---- slab-coalesced staging: thread t -> row t>>2, 8 floats at col (t&3)*8.
    // 512 threads x 8 floats = one 128x32 fp32 tile per matrix per K-step.
    // Per wave-instr: 16 rows x 4 lanes x 32B = rows of 128B contiguous: coalesced.
    const int lrow = tid >> 2;         // 0..127
    const int lcol = (tid & 3) * 8;    // float col within the 32-float K chunk

    const float* xg = X  + ((size_t)b * 8192 + m0 + lrow) * 512 + lcol;
    const float* wg = Wt + ((size_t)b * 512  + n0 + lrow) * 512 + lcol;

    f32x4 axl, axh, bxl, bxh;

    // ---- prologue: tile 0 -> buf 0 ----
    {
        axl = *(const f32x4*)(xg);
        axh = *(const f32x4*)(xg + 4);
        bxl = *(const f32x4*)(wg);
        bxh = *(const f32x4*)(wg + 4);
        i32x4 pa;
        pa[0] = pk2(axl[0], axl[1]); pa[1] = pk2(axl[2], axl[3]);
        pa[2] = pk2(axh[0], axh[1]); pa[3] = pk2(axh[2], axh[3]);
        *(i32x4*)&As[0][lrow * LDK + lcol] = pa;
        i32x4 pb;
        pb[0] = pk2(bxl[0], bxl[1]); pb[1] = pk2(bxl[2], bxl[3]);
        pb[2] = pk2(bxh[0], bxh[1]); pb[3] = pk2(bxh[2], bxh[3]);
        *(i32x4*)&Bs[0][lrow * LDK + lcol] = pb;
    }
    __syncthreads();

    f32x4 acc[4][2];
#pragma unroll
    for (int i = 0; i < 4; ++i)
#pragma unroll
        for (int j = 0; j < 2; ++j)
            acc[i][j] = (f32x4){0.f, 0.f, 0.f, 0.f};

    const int frow = lane & 15;
    const int fk   = (lane >> 4) * 8;

    const int KSTEPS = 512 / BK;   // 16
#pragma unroll 2
    for (int ks = 0; ks < KSTEPS; ++ks) {
        const int cur = ks & 1;
        const int nxt = cur ^ 1;

        // issue next tile's (coalesced) loads right after the barrier; consumed
        // after the MFMA section so ds_read+MFMA cover the load latency
        if (ks + 1 < KSTEPS) {
            axl = *(const f32x4*)(xg + (ks + 1) * BK);
            axh = *(const f32x4*)(xg + (ks + 1) * BK + 4);
            bxl = *(const f32x4*)(wg + (ks + 1) * BK);
            bxh = *(const f32x4*)(wg + (ks + 1) * BK + 4);
        }

        bf16x8 af[4], bfr[2];
#pragma unroll
        for (int mf = 0; mf < 4; ++mf)
            af[mf] = *(const bf16x8*)&As[cur][(wm + mf * 16 + frow) * LDK + fk];
#pragma unroll
        for (int nf = 0; nf < 2; ++nf)
            bfr[nf] = *(const bf16x8*)&Bs[cur][(wn + nf * 16 + frow) * LDK + fk];

#pragma unroll
        for (int mf = 0; mf < 4; ++mf)
#pragma unroll
            for (int nf = 0; nf < 2; ++nf)
                acc[mf][nf] = __builtin_amdgcn_mfma_f32_16x16x32_bf16(
                    af[mf], bfr[nf], acc[mf][nf], 0, 0, 0);

        if (ks + 1 < KSTEPS) {
            i32x4 pa;
            pa[0] = pk2(axl[0], axl[1]); pa[1] = pk2(axl[2], axl[3]);
            pa[2] = pk2(axh[0], axh[1]); pa[3] = pk2(axh[2], axh[3]);
            *(i32x4*)&As[nxt][lrow * LDK + lcol] = pa;
            i32x4 pb;
            pb[0] = pk2(bxl[0], bxl[1]); pb[1] = pk2(bxl[2], bxl[3]);
            pb[2] = pk2(bxh[0], bxh[1]); pb[3] = pk2(bxh[2], bxh[3]);
            *(i32x4*)&Bs[nxt][lrow * LDK + lcol] = pb;
        }

        __syncthreads();
    }

    // ---- epilogue: add bias, store fp32 ----
    float bv[2];
    const float* biasp = Bias + (size_t)b * 512 + n0 + wn;
#pragma unroll
    for (int nf = 0; nf < 2; ++nf)
        bv[nf] = biasp[nf * 16 + frow];

    float* outp = Out + ((size_t)b * 8192 + m0 + wm) * 512 + n0 + wn;
    const int orow = (lane >> 4) * 4;   // C/D: row = (lane>>4)*4 + reg
#pragma unroll
    for (int mf = 0; mf < 4; ++mf)
#pragma unroll
        for (int nf = 0; nf < 2; ++nf)
#pragma unroll
            for (int r = 0; r < 4; ++r)
                outp[(size_t)(mf * 16 + orow + r) * 512 + nf * 16 + frow] =
                    acc[mf][nf][r] + bv[nf];
}

extern "C" void kernel_launch(void* const* d_in, const int* in_sizes, int n_in,
                              void* d_out, int out_size, void* d_ws, size_t ws_size,
                              hipStream_t stream) {
    const float* X    = (const float*)d_in[0];
    const float* Wt   = (const float*)d_in[1];
    const float* Bias = (const float*)d_in[2];
    float* Out        = (float*)d_out;

    dim3 grid(2048);
    bgemm_bt_bias<<<grid, TB, 0, stream>>>(X, Wt, Bias, Out);
}